// Round 1
// baseline (194.261 us; speedup 1.0000x reference)
//
#include <hip/hip_runtime.h>
#include <hip/hip_bf16.h>

#define NHEADS 8
#define CDIM 256
#define HQ 32
#define WQ 32
#define HFD 128
#define WFD 128
#define BATCH 8

// ---------- helpers ----------
__device__ __forceinline__ float bflo(unsigned int u) { return __uint_as_float(u << 16); }
__device__ __forceinline__ float bfhi(unsigned int u) { return __uint_as_float(u & 0xffff0000u); }
__device__ __forceinline__ unsigned short f2bf(float f) {  // RNE
  unsigned int u = __float_as_uint(f);
  unsigned int r = (u + 0x7fffu + ((u >> 16) & 1u)) >> 16;
  return (unsigned short)r;
}
__device__ __forceinline__ void unpack8(uint4 v, float* f) {
  f[0] = bflo(v.x); f[1] = bfhi(v.x);
  f[2] = bflo(v.y); f[3] = bfhi(v.y);
  f[4] = bflo(v.z); f[5] = bfhi(v.z);
  f[6] = bflo(v.w); f[7] = bfhi(v.w);
}

// ---------- K0: transpose wq and wv (256x256) for coalesced reads ----------
__global__ __launch_bounds__(1024) void k_transpose2(const float* __restrict__ wq,
                                                     const float* __restrict__ wv,
                                                     float* __restrict__ wqT,
                                                     float* __restrict__ wvT) {
  __shared__ float tile[32][33];
  const float* src = (blockIdx.z == 0) ? wq : wv;
  float* dst = (blockIdx.z == 0) ? wqT : wvT;
  const int tx = threadIdx.x, ty = threadIdx.y;
  const int r0 = blockIdx.y * 32, c0 = blockIdx.x * 32;
  tile[ty][tx] = src[(size_t)(r0 + ty) * CDIM + c0 + tx];
  __syncthreads();
  dst[(size_t)(c0 + ty) * CDIM + r0 + tx] = tile[tx][ty];
}

// ---------- K1: q = (x @ WqT + bq)*scaling ; gw = sigmoid(x@wg + bg) ----------
__global__ __launch_bounds__(256) void k_qgw(const float* __restrict__ x,
                                             const float* __restrict__ wqT,
                                             const float* __restrict__ bq,
                                             const float* __restrict__ wg,
                                             const float* __restrict__ bg,
                                             float* __restrict__ q_ws,
                                             float* __restrict__ gw_ws) {
  __shared__ __align__(16) float xs[256][32];
  const int h = blockIdx.x, b = blockIdx.y;
  const int t = threadIdx.x;
  const float* xb = x + (size_t)b * CDIM * HQ * WQ + (size_t)h * WQ;
  for (int it = 0; it < 32; ++it) {
    int e = it * 256 + t;
    int cx = e >> 5, w = e & 31;
    xs[cx][w] = xb[(size_t)cx * (HQ * WQ) + w];
  }
  __syncthreads();
  float acc[32];
#pragma unroll
  for (int w = 0; w < 32; ++w) acc[w] = 0.f;
  const int c = t;
  for (int cx = 0; cx < 256; ++cx) {
    float wv = wqT[(size_t)cx * CDIM + c];
    const float4* xr = (const float4*)(&xs[cx][0]);
#pragma unroll
    for (int w4 = 0; w4 < 8; ++w4) {
      float4 xv = xr[w4];
      acc[w4 * 4 + 0] = fmaf(xv.x, wv, acc[w4 * 4 + 0]);
      acc[w4 * 4 + 1] = fmaf(xv.y, wv, acc[w4 * 4 + 1]);
      acc[w4 * 4 + 2] = fmaf(xv.z, wv, acc[w4 * 4 + 2]);
      acc[w4 * 4 + 3] = fmaf(xv.w, wv, acc[w4 * 4 + 3]);
    }
  }
  const float scaling = 0.17677669529663687f;  // 32^-0.5
  const float bqc = bq[c];
  float* qrow = q_ws + ((size_t)(b * CDIM + c) * HQ + h) * WQ;
#pragma unroll
  for (int w4 = 0; w4 < 8; ++w4) {
    float4 o;
    o.x = (acc[w4 * 4 + 0] + bqc) * scaling;
    o.y = (acc[w4 * 4 + 1] + bqc) * scaling;
    o.z = (acc[w4 * 4 + 2] + bqc) * scaling;
    o.w = (acc[w4 * 4 + 3] + bqc) * scaling;
    ((float4*)qrow)[w4] = o;
  }
  if (t < 32) {
    float a = bg[0];
    for (int cx = 0; cx < 256; ++cx) a = fmaf(xs[cx][t], wg[cx], a);
    gw_ws[(b * HQ + h) * WQ + t] = 1.f / (1.f + __expf(-a));
  }
}

// ---------- K2: fused local-grid attention ----------
// block = (h, w-octet, b): 8 query pixels, all heads. 512 threads.
// phases: stage q + feat(bf16) -> qk = q_head @ Wk_head -> logits = qk . feat
//         -> softmax(16) -> fa = attn-avg(feat) -> out = WvT' fa + bv, * gw
__global__ __launch_bounds__(512) void k_attn(const float* __restrict__ feat,
                                              const float* __restrict__ wk,
                                              const float* __restrict__ wvT,
                                              const float* __restrict__ bv,
                                              const float* __restrict__ q_ws,
                                              const float* __restrict__ gw_ws,
                                              float* __restrict__ out) {
  __shared__ __align__(16) float qs[256][8];                 // 8 KB
  __shared__ __align__(16) unsigned short featb[256 * 136];  // 69.6 KB  [ci][w*16+p], ci-stride padded 136
  __shared__ __align__(16) float qkfa[8 * 256 * 8];          // 64 KB    qk then fa: [hd][ci][w]
  __shared__ __align__(16) float logits_s[8 * 16 * 8];       // 4 KB     [hd][p][w]
  __shared__ __align__(16) float attn2[8 * 128];             // 4 KB     [w][hd*16+p]
  __shared__ float gws[8];

  const int h = blockIdx.x, w4b = blockIdx.y, b = blockIdx.z;
  const int t = threadIdx.x;

  // ---- P0: stage q row-octet + gate ----
  {
    const float* qb = q_ws + ((size_t)(b * CDIM) * HQ + h) * WQ + w4b * 8;
#pragma unroll
    for (int it = 0; it < 4; ++it) {
      int e = it * 512 + t;
      int c = e >> 3, wl = e & 7;
      qs[c][wl] = qb[(size_t)c * (HQ * WQ) + wl];
    }
    if (t < 8) gws[t] = gw_ws[(b * HQ + h) * WQ + w4b * 8 + t];
  }
  // ---- P1: stage feat patch (4 rows x 32 cols x 256 ch) as bf16 ----
  {
    const float* fb = feat + (size_t)b * CDIM * HFD * WFD + (size_t)(h * 4) * WFD + w4b * 32;
#pragma unroll
    for (int it = 0; it < 16; ++it) {
      int e = it * 512 + t;
      int ci = e >> 5, rem = e & 31, r = rem >> 3, j4 = rem & 7;
      float4 v = *(const float4*)(fb + (size_t)ci * (HFD * WFD) + r * WFD + j4 * 4);
      ushort4 pk;
      pk.x = f2bf(v.x); pk.y = f2bf(v.y); pk.z = f2bf(v.z); pk.w = f2bf(v.w);
      // pixel wloc=j4, grid pos p = r*4+e  -> contiguous 4 bf16
      *(ushort4*)(&featb[ci * 136 + j4 * 16 + r * 4]) = pk;
    }
  }
  __syncthreads();

  // ---- P2: qk[hd][ci][w] = sum_j q[hd*32+j][w] * Wk[hd*32+j][ci] ----
  {
    const int ci = t & 255, hq = t >> 8;  // hq in {0,1} -> 4 heads each
    float acc[4][8];
#pragma unroll
    for (int k = 0; k < 4; ++k)
#pragma unroll
      for (int w = 0; w < 8; ++w) acc[k][w] = 0.f;
    for (int j = 0; j < 32; ++j) {
#pragma unroll
      for (int k = 0; k < 4; ++k) {
        const int row = (hq * 4 + k) * 32 + j;
        float wkv = wk[(size_t)row * CDIM + ci];  // coalesced, L2-resident
        const float4* q4 = (const float4*)(&qs[row][0]);
        float4 a = q4[0], d = q4[1];
        acc[k][0] = fmaf(a.x, wkv, acc[k][0]);
        acc[k][1] = fmaf(a.y, wkv, acc[k][1]);
        acc[k][2] = fmaf(a.z, wkv, acc[k][2]);
        acc[k][3] = fmaf(a.w, wkv, acc[k][3]);
        acc[k][4] = fmaf(d.x, wkv, acc[k][4]);
        acc[k][5] = fmaf(d.y, wkv, acc[k][5]);
        acc[k][6] = fmaf(d.z, wkv, acc[k][6]);
        acc[k][7] = fmaf(d.w, wkv, acc[k][7]);
      }
    }
#pragma unroll
    for (int k = 0; k < 4; ++k) {
      const int hd = hq * 4 + k;
      float* dst = &qkfa[(hd * 256 + ci) * 8];
      ((float4*)dst)[0] = make_float4(acc[k][0], acc[k][1], acc[k][2], acc[k][3]);
      ((float4*)dst)[1] = make_float4(acc[k][4], acc[k][5], acc[k][6], acc[k][7]);
    }
  }
  __syncthreads();

  // ---- P3: logits[hd][p][w] = sum_ci qk[hd][ci][w] * feat[ci][w][p] ----
  {
    const int w = t & 7, cip = (t >> 3) & 7, hp = (t >> 6) & 3, ph = t >> 8;
    const int hd0 = hp * 2, hd1 = hd0 + 1;
    float a0[8], a1[8];
#pragma unroll
    for (int r = 0; r < 8; ++r) { a0[r] = 0.f; a1[r] = 0.f; }
    for (int i = 0; i < 32; ++i) {
      const int ci = cip * 32 + i;
      float qk0 = qkfa[(hd0 * 256 + ci) * 8 + w];
      float qk1 = qkfa[(hd1 * 256 + ci) * 8 + w];
      uint4 fv = *(const uint4*)(&featb[ci * 136 + w * 16 + ph * 8]);
      float f[8];
      unpack8(fv, f);
#pragma unroll
      for (int r = 0; r < 8; ++r) {
        a0[r] = fmaf(qk0, f[r], a0[r]);
        a1[r] = fmaf(qk1, f[r], a1[r]);
      }
    }
    // reduce over cip (lane bits 3..5) within the wave
#pragma unroll
    for (int m = 8; m <= 32; m <<= 1) {
#pragma unroll
      for (int r = 0; r < 8; ++r) {
        a0[r] += __shfl_xor(a0[r], m, 64);
        a1[r] += __shfl_xor(a1[r], m, 64);
      }
    }
    if (cip == 0) {
#pragma unroll
      for (int r = 0; r < 8; ++r) {
        const int p = ph * 8 + r;
        logits_s[(hd0 * 16 + p) * 8 + w] = a0[r];
        logits_s[(hd1 * 16 + p) * 8 + w] = a1[r];
      }
    }
  }
  __syncthreads();

  // ---- P4: softmax over 16 grid positions (bk dropped: constant shift) ----
  if (t < 64) {
    const int hd = t >> 3, w = t & 7;
    float l[16];
#pragma unroll
    for (int p = 0; p < 16; ++p) l[p] = logits_s[(hd * 16 + p) * 8 + w];
    float mx = l[0];
#pragma unroll
    for (int p = 1; p < 16; ++p) mx = fmaxf(mx, l[p]);
    float s = 0.f;
#pragma unroll
    for (int p = 0; p < 16; ++p) { l[p] = __expf(l[p] - mx); s += l[p]; }
    const float inv = 1.f / s;
    float* dst = &attn2[w * 128 + hd * 16];
#pragma unroll
    for (int p = 0; p < 16; ++p) dst[p] = l[p] * inv;
  }
  __syncthreads();

  // ---- P5: fa[hd][ci][w] = sum_p attn[hd][p][w] * feat[ci][w][p] (into qkfa) ----
  {
    const int ci = t & 255, hq = t >> 8;
    float acc[4][8];
#pragma unroll
    for (int w = 0; w < 8; ++w) {
      uint4 u0 = *(const uint4*)(&featb[ci * 136 + w * 16]);
      uint4 u1 = *(const uint4*)(&featb[ci * 136 + w * 16 + 8]);
      float f[16];
      unpack8(u0, f);
      unpack8(u1, f + 8);
#pragma unroll
      for (int k = 0; k < 4; ++k) {
        const float* at = &attn2[w * 128 + (hq * 4 + k) * 16];  // broadcast reads
        float s = 0.f;
#pragma unroll
        for (int p = 0; p < 16; ++p) s = fmaf(at[p], f[p], s);
        acc[k][w] = s;
      }
    }
#pragma unroll
    for (int k = 0; k < 4; ++k) {
      const int hd = hq * 4 + k;
      float* dst = &qkfa[(hd * 256 + ci) * 8];
      ((float4*)dst)[0] = make_float4(acc[k][0], acc[k][1], acc[k][2], acc[k][3]);
      ((float4*)dst)[1] = make_float4(acc[k][4], acc[k][5], acc[k][6], acc[k][7]);
    }
  }
  __syncthreads();

  // ---- P6: out[c][w] = (sum_ci Wv[c][ci]*fa[hd(c)][ci][w] + bv[c]) * gw[w] ----
  {
    const int c = t & 255, wh = t >> 8;
    const int hd = c >> 5;
    const float bvc = bv[c];
    float acc0 = bvc, acc1 = bvc, acc2 = bvc, acc3 = bvc;
    for (int ci = 0; ci < 256; ++ci) {
      float wv = wvT[(size_t)ci * CDIM + c];  // coalesced
      float4 fv = *(const float4*)(&qkfa[(hd * 256 + ci) * 8 + wh * 4]);  // broadcast
      acc0 = fmaf(wv, fv.x, acc0);
      acc1 = fmaf(wv, fv.y, acc1);
      acc2 = fmaf(wv, fv.z, acc2);
      acc3 = fmaf(wv, fv.w, acc3);
    }
    float4 o;
    o.x = acc0 * gws[wh * 4 + 0];
    o.y = acc1 * gws[wh * 4 + 1];
    o.z = acc2 * gws[wh * 4 + 2];
    o.w = acc3 * gws[wh * 4 + 3];
    float* ob = out + ((size_t)(b * CDIM + c) * HQ + h) * WQ + w4b * 8 + wh * 4;
    *(float4*)ob = o;
  }
}

// ---------- launcher ----------
extern "C" void kernel_launch(void* const* d_in, const int* in_sizes, int n_in,
                              void* d_out, int out_size, void* d_ws, size_t ws_size,
                              hipStream_t stream) {
  const float* x = (const float*)d_in[0];
  const float* feat = (const float*)d_in[1];
  const float* wq = (const float*)d_in[2];
  const float* bq = (const float*)d_in[3];
  const float* wk = (const float*)d_in[4];
  // d_in[5] = bk: constant over grid positions -> cancels in softmax, unused
  const float* wv = (const float*)d_in[6];
  const float* bv = (const float*)d_in[7];
  const float* wg = (const float*)d_in[8];
  const float* bg = (const float*)d_in[9];
  float* out = (float*)d_out;

  float* ws = (float*)d_ws;
  float* q_ws = ws;                        // 2097152 f32
  float* gw_ws = ws + 2097152;             // 8192 f32
  float* wqT = gw_ws + 8192;               // 65536 f32
  float* wvT = wqT + 65536;                // 65536 f32  (total ~8.9 MB)

  hipLaunchKernelGGL(k_transpose2, dim3(8, 8, 2), dim3(32, 32), 0, stream, wq, wv, wqT, wvT);
  hipLaunchKernelGGL(k_qgw, dim3(32, 8), dim3(256), 0, stream, x, wqT, bq, wg, bg, q_ws, gw_ws);
  // grid order: h fastest so the 4 w-octet siblings of a row land 32 apart
  // (same XCD under round-robin) for L2 write-combining of partial out lines
  hipLaunchKernelGGL(k_attn, dim3(32, 4, 8), dim3(512), 0, stream, feat, wk, wvT, bv, q_ws,
                     gw_ws, out);
}

// Round 2
// 144.854 us; speedup vs baseline: 1.3411x; 1.3411x over previous
//
#include <hip/hip_runtime.h>

#define NHEADS 8
#define CDIM 256
#define HQ 32
#define WQ 32
#define HFD 128
#define WFD 128
#define BATCH 8
#define SCALING 0.17677669529663687f  // 32^-0.5

typedef _Float16 half2v __attribute__((ext_vector_type(2)));
union H2U { unsigned int u; half2v h; unsigned short s[2]; };

#if __has_builtin(__builtin_amdgcn_fdot2)
__device__ __forceinline__ float FDOT2(half2v a, half2v b, float c) {
  return __builtin_amdgcn_fdot2(a, b, c, false);
}
#else
__device__ __forceinline__ float FDOT2(half2v a, half2v b, float c) {
  return fmaf((float)a.x, (float)b.x, fmaf((float)a.y, (float)b.y, c));
}
#endif

// ---------------- K0: weight prep ----------------
// z=0: wqT2 = f16-pair-packed transpose of wq, pre-scaled; bqs = bq*scaling
// z=1: wkh  = f16 copy of wk (no transpose)
// z=2: wv2  = f16-pair-packed transpose of wv
__global__ __launch_bounds__(1024) void k_prep(const float* __restrict__ wq,
                                               const float* __restrict__ bq,
                                               const float* __restrict__ wk,
                                               const float* __restrict__ wv,
                                               unsigned short* __restrict__ wqh,
                                               float* __restrict__ bqs,
                                               _Float16* __restrict__ wkh,
                                               unsigned short* __restrict__ wvh) {
  __shared__ float tile[32][33];
  const int tx = threadIdx.x, ty = threadIdx.y;
  const int bx = blockIdx.x, by = blockIdx.y, z = blockIdx.z;
  if (z == 1) {
    int idx = (by * 32 + ty) * CDIM + bx * 32 + tx;
    wkh[idx] = (_Float16)wk[idx];
    if (bx == 0 && by == 0 && ty < 8) {
      int i = ty * 32 + tx;
      bqs[i] = bq[i] * SCALING;
    }
    return;
  }
  const float* src = (z == 0) ? wq : wv;
  tile[ty][tx] = src[(size_t)(by * 32 + ty) * CDIM + bx * 32 + tx];
  __syncthreads();
  // tile[tx][ty] = src[by*32+tx][bx*32+ty]  (row = out-ch c, col = in-ch)
  int cin = bx * 32 + ty;  // in-channel (cx for wq, ci for wv)
  int c = by * 32 + tx;    // out-channel
  float v = tile[tx][ty];
  if (z == 0) v *= SCALING;
  unsigned short* dst = (z == 0) ? wqh : wvh;
  union { _Float16 h; unsigned short s; } cv;
  cv.h = (_Float16)v;
  dst[(cin >> 1) * 512 + c * 2 + (cin & 1)] = cv.s;
}

// ---------------- K1: q = (x@wq + bq)*scaling ; gw = sigmoid(x@wg + bg) ----
// grid (32 h, 2 w-half, 8 b), 256 threads
__global__ __launch_bounds__(256) void k_qgw(const float* __restrict__ x,
                                             const unsigned int* __restrict__ wqT2,
                                             const float* __restrict__ bqs,
                                             const float* __restrict__ wg,
                                             const float* __restrict__ bg,
                                             float* __restrict__ q_ws,
                                             float* __restrict__ gw_ws) {
  __shared__ unsigned int xs2[128][20];  // f16 pairs over cx; stride 20 (16B-aligned, odd/32 banks)
  const int h = blockIdx.x, wh = blockIdx.y, b = blockIdx.z;
  const int t = threadIdx.x;
  const float* xb = x + (size_t)b * (CDIM * HQ * WQ) + (size_t)h * WQ + wh * 16;
#pragma unroll
  for (int it = 0; it < 2; ++it) {
    int e = it * 256 + t;
    int j4 = e & 3, cx2 = e >> 2;  // 128 cx-pairs x 4 float4s
    float4 v0 = *(const float4*)(xb + (size_t)(2 * cx2) * (HQ * WQ) + j4 * 4);
    float4 v1 = *(const float4*)(xb + (size_t)(2 * cx2 + 1) * (HQ * WQ) + j4 * 4);
    H2U p0, p1, p2, p3;
    p0.h.x = (_Float16)v0.x; p0.h.y = (_Float16)v1.x;
    p1.h.x = (_Float16)v0.y; p1.h.y = (_Float16)v1.y;
    p2.h.x = (_Float16)v0.z; p2.h.y = (_Float16)v1.z;
    p3.h.x = (_Float16)v0.w; p3.h.y = (_Float16)v1.w;
    xs2[cx2][j4 * 4 + 0] = p0.u;
    xs2[cx2][j4 * 4 + 1] = p1.u;
    xs2[cx2][j4 * 4 + 2] = p2.u;
    xs2[cx2][j4 * 4 + 3] = p3.u;
  }
  __syncthreads();
  const int c = t;
  float acc[16];
#pragma unroll
  for (int j = 0; j < 16; ++j) acc[j] = 0.f;
  for (int cx2 = 0; cx2 < 128; ++cx2) {
    H2U wqp;
    wqp.u = wqT2[cx2 * 256 + c];  // coalesced, L2-resident
#pragma unroll
    for (int j = 0; j < 16; ++j) {
      H2U xv;
      xv.u = xs2[cx2][j];  // broadcast
      acc[j] = FDOT2(xv.h, wqp.h, acc[j]);
    }
  }
  const float bqc = bqs[c];
  float* qrow = q_ws + ((size_t)(b * CDIM + c) * HQ + h) * WQ + wh * 16;
#pragma unroll
  for (int j4 = 0; j4 < 4; ++j4) {
    float4 o;
    o.x = acc[j4 * 4 + 0] + bqc;
    o.y = acc[j4 * 4 + 1] + bqc;
    o.z = acc[j4 * 4 + 2] + bqc;
    o.w = acc[j4 * 4 + 3] + bqc;
    ((float4*)qrow)[j4] = o;
  }
  if (t < 32) {
    int w = t & 15, hf = t >> 4;
    float a = 0.f;
    for (int cx2 = hf * 64; cx2 < hf * 64 + 64; ++cx2) {
      H2U xv;
      xv.u = xs2[cx2][w];
      a = fmaf((float)xv.h.x, wg[2 * cx2], a);
      a = fmaf((float)xv.h.y, wg[2 * cx2 + 1], a);
    }
    a += __shfl_xor(a, 16, 64);
    if (t < 16)
      gw_ws[((size_t)b * HQ + h) * WQ + wh * 16 + w] = 1.f / (1.f + __expf(-(a + bg[0])));
  }
}

// ---------------- K2: fused local-grid attention ----------------
// block = (h, w-quad, b): 4 query pixels, all heads, 256 threads, 52.4 KB LDS
// (3 blocks/CU). Phases: P1 stage feat f16 | P2 qk = Wk_head^T q (f32->f16)
// | barrier | P3 logits + in-wave softmax | barrier | P5 fa = attn-avg(feat)
// | barrier | P6 out = Wv^T fa + bv, * gw
#define FWS 2056  // feat w-group stride in u32: 8*256 + 8 (bank offset 8/w)
__global__ __launch_bounds__(256, 3) void k_attn(const float* __restrict__ feat,
                                                 const _Float16* __restrict__ wkh,
                                                 const unsigned int* __restrict__ wv2,
                                                 const float* __restrict__ bv,
                                                 const float* __restrict__ q_ws,
                                                 const float* __restrict__ gw_ws,
                                                 float* __restrict__ out) {
  __shared__ __align__(16) unsigned int featb[8216];     // 32864 B  [w][k][ci] f16-pair(p=k lo, p=k+8 hi)
  __shared__ __align__(16) unsigned short qkfa[8704];    // 17408 B  qk: [ci][34] -> fa: [pair][264]
  __shared__ __align__(16) float attns[32 * 17];         //  2176 B  [pair][17]
  const int t = threadIdx.x;
  const int h = blockIdx.x, w4 = blockIdx.y, b = blockIdx.z;

  // ---- P1: stage 4x16-pixel feat patch as f16 ----
  {
    const float* fb = feat + (size_t)b * (CDIM * HFD * WFD) + (size_t)(h * 4) * WFD + w4 * 16;
    _Float16* fs = (_Float16*)featb;
#pragma unroll 4
    for (int it = 0; it < 16; ++it) {
      int e = it * 256 + t;
      int j4 = e & 3, r = (e >> 2) & 3, ci = e >> 4;
      float4 v = *(const float4*)(fb + (size_t)ci * (HFD * WFD) + r * WFD + j4 * 4);
      // p = r*4 + wloc; slot k = (r&1)*4 + wloc; half = r>>1
      int half = r >> 1;
      int u32base = j4 * FWS + ((r & 1) * 4) * 256 + ci;
      fs[2 * (u32base + 0 * 256) + half] = (_Float16)v.x;
      fs[2 * (u32base + 1 * 256) + half] = (_Float16)v.y;
      fs[2 * (u32base + 2 * 256) + half] = (_Float16)v.z;
      fs[2 * (u32base + 3 * 256) + half] = (_Float16)v.w;
    }
  }

  // ---- P2: qk[ci=t][hd*4+w] = sum_j q[hd*32+j][w] * wk[hd*32+j][ci] ----
  {
    float acc[8][4];
#pragma unroll
    for (int hd = 0; hd < 8; ++hd) {
      acc[hd][0] = 0.f; acc[hd][1] = 0.f; acc[hd][2] = 0.f; acc[hd][3] = 0.f;
    }
    const float* qb = q_ws + (size_t)b * (CDIM * HQ * WQ) + (size_t)h * WQ + w4 * 4;
#pragma unroll
    for (int hd = 0; hd < 8; ++hd) {
#pragma unroll 4
      for (int j = 0; j < 32; ++j) {
        int row = hd * 32 + j;
        float wkv = (float)wkh[row * 256 + t];               // coalesced u16
        float4 qv = *(const float4*)(qb + (size_t)row * (HQ * WQ));  // lane-uniform -> scalar
        acc[hd][0] = fmaf(qv.x, wkv, acc[hd][0]);
        acc[hd][1] = fmaf(qv.y, wkv, acc[hd][1]);
        acc[hd][2] = fmaf(qv.z, wkv, acc[hd][2]);
        acc[hd][3] = fmaf(qv.w, wkv, acc[hd][3]);
      }
    }
    unsigned int* qk32 = (unsigned int*)qkfa;  // [ci][34] u16 = [ci][17] u32
#pragma unroll
    for (int hd = 0; hd < 8; ++hd) {
      H2U u0, u1;
      u0.h.x = (_Float16)acc[hd][0]; u0.h.y = (_Float16)acc[hd][1];
      u1.h.x = (_Float16)acc[hd][2]; u1.h.y = (_Float16)acc[hd][3];
      qk32[t * 17 + hd * 2 + 0] = u0.u;
      qk32[t * 17 + hd * 2 + 1] = u1.u;
    }
  }
  __syncthreads();

  const int lane = t & 63, wave = t >> 6;
  const int pl = lane & 7, chunk = lane >> 3;  // 8 pairs x 8 ci-chunks per wave
  const int pair = wave * 8 + pl;              // hd*4 + w
  const int wl = pair & 3;

  // ---- P3: logits[pair][p] = sum_ci qk[ci][pair]*feat[p][wl][ci]; softmax ----
  {
    float part[16];
#pragma unroll
    for (int p = 0; p < 16; ++p) part[p] = 0.f;
    const unsigned int* fw = featb + wl * FWS;
    const _Float16* qkh = (const _Float16*)qkfa;
    for (int i = 0; i < 32; ++i) {
      int ci = i * 8 + chunk;  // interleaved: in-wave banks stay distinct
      float qkv = (float)qkh[ci * 34 + pair];
#pragma unroll
      for (int k = 0; k < 8; ++k) {
        H2U u;
        u.u = fw[k * 256 + ci];
        part[k] = fmaf(qkv, (float)u.h.x, part[k]);
        part[k + 8] = fmaf(qkv, (float)u.h.y, part[k + 8]);
      }
    }
#pragma unroll
    for (int p = 0; p < 16; ++p) {
      part[p] += __shfl_xor(part[p], 8, 64);
      part[p] += __shfl_xor(part[p], 16, 64);
      part[p] += __shfl_xor(part[p], 32, 64);
    }
    if (chunk == 0) {
      float mx = part[0];
#pragma unroll
      for (int p = 1; p < 16; ++p) mx = fmaxf(mx, part[p]);
      float s = 0.f;
#pragma unroll
      for (int p = 0; p < 16; ++p) {
        part[p] = __expf(part[p] - mx);
        s += part[p];
      }
      float inv = 1.f / s;
#pragma unroll
      for (int p = 0; p < 16; ++p) attns[pair * 17 + p] = part[p] * inv;
    }
  }
  __syncthreads();

  // ---- P5: fa[pair][ci] = sum_p attn[pair][p]*feat[p][wl][ci]  (f16, reuses qk buf) ----
  {
    half2v at[8];
#pragma unroll
    for (int k = 0; k < 8; ++k) {
      at[k].x = (_Float16)attns[pair * 17 + k];
      at[k].y = (_Float16)attns[pair * 17 + k + 8];
    }
    const unsigned int* fw = featb + wl * FWS;
    _Float16* fah = (_Float16*)qkfa;  // [pair][264]
    for (int i = 0; i < 32; ++i) {
      int ci = i * 8 + chunk;
      float s = 0.f;
#pragma unroll
      for (int k = 0; k < 8; ++k) {
        H2U u;
        u.u = fw[k * 256 + ci];
        s = FDOT2(at[k], u.h, s);
      }
      fah[pair * 264 + ci] = (_Float16)s;
    }
  }
  __syncthreads();

  // ---- P6: out[c][w] = (sum_ci wv[c][ci]*fa[hd*4+w][ci] + bv[c]) * gw[w] ----
  {
    const int c = t, hd = c >> 5;
    const unsigned int* fa32 = (const unsigned int*)qkfa;  // [pair][132] u32
    const int fb0 = (hd * 4) * 132;
    float a0 = 0.f, a1 = 0.f, a2 = 0.f, a3 = 0.f;
    for (int ci2 = 0; ci2 < 128; ++ci2) {
      H2U wp;
      wp.u = wv2[ci2 * 256 + c];  // coalesced f16 pair (ci even, odd)
      H2U f0, f1, f2, f3;
      f0.u = fa32[fb0 + 0 * 132 + ci2];  // broadcast
      f1.u = fa32[fb0 + 1 * 132 + ci2];
      f2.u = fa32[fb0 + 2 * 132 + ci2];
      f3.u = fa32[fb0 + 3 * 132 + ci2];
      a0 = FDOT2(f0.h, wp.h, a0);
      a1 = FDOT2(f1.h, wp.h, a1);
      a2 = FDOT2(f2.h, wp.h, a2);
      a3 = FDOT2(f3.h, wp.h, a3);
    }
    float bvc = bv[c];
    const float* gp = gw_ws + ((size_t)b * HQ + h) * WQ + w4 * 4;
    float4 o;
    o.x = (a0 + bvc) * gp[0];
    o.y = (a1 + bvc) * gp[1];
    o.z = (a2 + bvc) * gp[2];
    o.w = (a3 + bvc) * gp[3];
    float* ob = out + ((size_t)(b * CDIM + c) * HQ + h) * WQ + w4 * 4;
    *(float4*)ob = o;
  }
}

// ---------------- launcher ----------------
extern "C" void kernel_launch(void* const* d_in, const int* in_sizes, int n_in,
                              void* d_out, int out_size, void* d_ws, size_t ws_size,
                              hipStream_t stream) {
  const float* x = (const float*)d_in[0];
  const float* feat = (const float*)d_in[1];
  const float* wq = (const float*)d_in[2];
  const float* bq = (const float*)d_in[3];
  const float* wk = (const float*)d_in[4];
  // d_in[5] = bk: constant over grid positions -> cancels in softmax, unused
  const float* wv = (const float*)d_in[6];
  const float* bv = (const float*)d_in[7];
  const float* wg = (const float*)d_in[8];
  const float* bg = (const float*)d_in[9];
  float* out = (float*)d_out;

  char* ws = (char*)d_ws;
  float* q_ws = (float*)ws;                                   // 8388608 B
  float* gw_ws = (float*)(ws + 8388608);                      //   32768 B
  float* bqs = (float*)(ws + 8421376);                        //    1024 B
  unsigned short* wqT2 = (unsigned short*)(ws + 8422400);     //  131072 B (u32[32768])
  _Float16* wkh = (_Float16*)(ws + 8553472);                  //  131072 B
  unsigned short* wv2 = (unsigned short*)(ws + 8684544);      //  131072 B

  hipLaunchKernelGGL(k_prep, dim3(8, 8, 3), dim3(32, 32), 0, stream, wq, bq, wk, wv, wqT2, bqs,
                     wkh, wv2);
  hipLaunchKernelGGL(k_qgw, dim3(32, 2, 8), dim3(256), 0, stream, x, (const unsigned int*)wqT2,
                     bqs, wg, bg, q_ws, gw_ws);
  hipLaunchKernelGGL(k_attn, dim3(32, 8, 8), dim3(256), 0, stream, feat, wkh,
                     (const unsigned int*)wv2, bv, q_ws, gw_ws, out);
}

// Round 5
// 88.205 us; speedup vs baseline: 2.2024x; 1.6422x over previous
//
#include <hip/hip_runtime.h>

#define CDIM 256
#define SCALING 0.17677669529663687f  // 32^-0.5

typedef _Float16 f16;
typedef f16 f16x4 __attribute__((ext_vector_type(4)));
typedef f16 f16x8 __attribute__((ext_vector_type(8)));
typedef float f32x4 __attribute__((ext_vector_type(4)));

// Standard gfx950 16x16x32 f16 fragment mapping (m89-verified D; ladder-verified A/B):
//   A[m][k]: lane l, reg j  ->  m = l&15,            k = 8*(l>>4) + j   (k contiguous)
//   B[k][n]: lane l, reg j  ->  k = 8*(l>>4) + j,    n = l&15           (k contiguous)
//   D[m][n]: lane l, reg r  ->  m = 4*(l>>4) + r,    n = l&15
#define MFMA(a, b, c) __builtin_amdgcn_mfma_f32_16x16x32_f16(a, b, c, 0, 0, 0)

// ---------------- K0a: W2_hd = scaling * wk_hd^T @ wq_hd ; b2 = scaling * wk_hd^T bq_hd ----
__global__ __launch_bounds__(256) void k_prep_w2(const float* __restrict__ wq,
                                                 const float* __restrict__ bq,
                                                 const float* __restrict__ wk,
                                                 f16* __restrict__ W2h,
                                                 float* __restrict__ b2) {
  __shared__ float wk_s[32][8];
  const int t = threadIdx.x, ciO = blockIdx.x, hd = blockIdx.y;
  {
    int j = t >> 3, c8 = t & 7;
    wk_s[j][c8] = wk[(hd * 32 + j) * CDIM + ciO * 8 + c8];
  }
  float wq_r[32];
#pragma unroll
  for (int j = 0; j < 32; ++j) wq_r[j] = wq[(hd * 32 + j) * CDIM + t];
  __syncthreads();
  for (int c8 = 0; c8 < 8; ++c8) {
    float acc = 0.f;
#pragma unroll
    for (int j = 0; j < 32; ++j) acc = fmaf(wq_r[j], wk_s[j][c8], acc);
    W2h[(size_t)(hd * CDIM + ciO * 8 + c8) * CDIM + t] = (f16)(acc * SCALING);
  }
  if (t < 8) {
    float a = 0.f;
    for (int j = 0; j < 32; ++j) a = fmaf(wk_s[j][t], bq[hd * 32 + j], a);
    b2[hd * CDIM + ciO * 8 + t] = a * SCALING;
  }
}

// ---------------- K0b: wv -> f16 (row-major [c][ci]) ----------------
__global__ __launch_bounds__(256) void k_cvt_wv(const float* __restrict__ wv,
                                                f16* __restrict__ wvh) {
  int i = (blockIdx.x * 256 + threadIdx.x) * 4;
  float4 v = *(const float4*)(wv + i);
  f16x4 h;
  h[0] = (f16)v.x; h[1] = (f16)v.y; h[2] = (f16)v.z; h[3] = (f16)v.w;
  *(f16x4*)(wvh + i) = h;
}

// ---------------- K1: qk[b][pix][hd][ci] = W2_hd @ x + b2 ; gate ----------------
// grid (16 pix-64-slices, 8 hd, nb) x 256. M=256ci, N=64pix, K=256cx.
__global__ __launch_bounds__(256, 2) void k_qkw2(const float* __restrict__ x,
                                                 const f16* __restrict__ W2h,
                                                 const float* __restrict__ b2,
                                                 const float* __restrict__ wg,
                                                 const float* __restrict__ bg,
                                                 f16* __restrict__ qk,
                                                 float* __restrict__ gw, int b0) {
  __shared__ __align__(16) f16 A_l[256 * 40];  // [ci][32cx + 8 pad]  20480 B
  __shared__ __align__(16) f16 B_l[64 * 40];   // [pix][32cx + 8 pad]  5120 B
  const int t = threadIdx.x;
  const int p16 = blockIdx.x, hd = blockIdx.y, bz = blockIdx.z;
  const int bb = b0 + bz;
  const int lane = t & 63, wid = t >> 6, l15 = lane & 15, h4 = lane >> 4;
  f32x4 acc[4][4] = {};
  float gacc = 0.f;

  for (int kb = 0; kb < 8; ++kb) {
    __syncthreads();
    // stage A: W2_hd[:, kb*32 .. +32] (16 KB)
#pragma unroll
    for (int it = 0; it < 4; ++it) {
      int e = it * 256 + t, ci = e >> 2, q = e & 3;
      *(f16x8*)(A_l + ci * 40 + q * 8) =
          *(const f16x8*)(W2h + (size_t)(hd * CDIM + ci) * CDIM + kb * 32 + q * 8);
    }
    // stage B transposed: x[kb*32+cx][p16*64 + p] -> B_l[p][cx]
#pragma unroll
    for (int it = 0; it < 2; ++it) {
      int e = it * 256 + t, cx = e >> 4, p4 = e & 15;
      float4 v = *(const float4*)(x + (size_t)(bb * CDIM + kb * 32 + cx) * 1024 +
                                  p16 * 64 + p4 * 4);
      B_l[(p4 * 4 + 0) * 40 + cx] = (f16)v.x;
      B_l[(p4 * 4 + 1) * 40 + cx] = (f16)v.y;
      B_l[(p4 * 4 + 2) * 40 + cx] = (f16)v.z;
      B_l[(p4 * 4 + 3) * 40 + cx] = (f16)v.w;
    }
    __syncthreads();
    // gate partial (hd==0, wave 3): pixel = lane
    if (hd == 0 && wid == 3) {
#pragma unroll
      for (int cx = 0; cx < 32; ++cx)
        gacc = fmaf(wg[kb * 32 + cx], (float)B_l[lane * 40 + cx], gacc);
    }
    f16x8 a[4], bf[4];
#pragma unroll
    for (int mt = 0; mt < 4; ++mt)
      a[mt] = *(const f16x8*)(A_l + (wid * 64 + mt * 16 + l15) * 40 + h4 * 8);
#pragma unroll
    for (int nt = 0; nt < 4; ++nt)
      bf[nt] = *(const f16x8*)(B_l + (nt * 16 + l15) * 40 + h4 * 8);
#pragma unroll
    for (int mt = 0; mt < 4; ++mt)
#pragma unroll
      for (int nt = 0; nt < 4; ++nt) acc[mt][nt] = MFMA(a[mt], bf[nt], acc[mt][nt]);
  }
  // epilogue: + b2, f16, store qk[b][pix][hd][ci]
#pragma unroll
  for (int mt = 0; mt < 4; ++mt) {
    int ci0 = wid * 64 + mt * 16 + h4 * 4;
    float4 bvv = *(const float4*)(b2 + hd * CDIM + ci0);
#pragma unroll
    for (int nt = 0; nt < 4; ++nt) {
      int pix = p16 * 64 + nt * 16 + l15;
      union { f16 h[4]; unsigned long long u; } P;
      P.h[0] = (f16)(acc[mt][nt][0] + bvv.x);
      P.h[1] = (f16)(acc[mt][nt][1] + bvv.y);
      P.h[2] = (f16)(acc[mt][nt][2] + bvv.z);
      P.h[3] = (f16)(acc[mt][nt][3] + bvv.w);
      *(unsigned long long*)(qk + ((size_t)(bz * 1024 + pix) * 8 + hd) * CDIM + ci0) = P.u;
    }
  }
  if (hd == 0 && wid == 3)
    gw[bz * 1024 + p16 * 64 + lane] = 1.f / (1.f + __expf(-(gacc + bg[0])));
}

// ---------------- K2: fused local attention (MFMA, plain loads only) ----------------
// block (h, w4, b): 4 query pixels, wave w owns pixel w. One barrier, no asm.
// Feat patch staged in BOTH layouts (it's tiny):
//   cip: [w][256ci][16p]   -> P5 A-fragments ([ci][p], k=p contiguous)
//   pci: [w][16p][256ci]   -> P3 B-fragments ([p][ci], k=ci contiguous)
// P3: logits[16hd][16p] = qk[16hd][256ci] @ feat[256ci][16p]   (8 MFMA, A from global)
// P5: fa[256ci][16hd]   = feat[256ci][16p(pad32)] @ attnT[32p][16hd] (16 MFMA)
__global__ __launch_bounds__(256, 2) void k_attn(const float* __restrict__ feat,
                                                 const f16* __restrict__ qk,
                                                 f16* __restrict__ fa, int b0) {
  __shared__ __align__(16) f16 featb_cip[4 * 4128];  // 33024 B  [w][ci][16p] +32 zero pad/w
  __shared__ __align__(16) f16 featb_pci[4 * 4224];  // 33792 B  [w][p][256ci +8 pad]
  __shared__ __align__(16) f16 attn_l[4 * 16 * 32];  //  4096 B  [w][16hd][32p]
  const int t = threadIdx.x;
  const int h = blockIdx.x, w4 = blockIdx.y, bz = blockIdx.z;
  const int bb = b0 + bz;
  const int lane = t & 63, w = t >> 6, l15 = lane & 15, h4 = lane >> 4;
  const int pixb = h * 32 + w4 * 4;

  {  // zero attn buffer (p>=16 stays 0 = K-padding; hd>=8 stays 0)
    f16x8 z = {};
    *(f16x8*)(attn_l + t * 8) = z;
  }
  if (t < 128) {  // zero cip pad (P5 A k=16..31 of each w's last ci row reads it)
    int wi = t >> 5, i = t & 31;
    featb_cip[wi * 4128 + 4096 + i] = (f16)0;
  }
  // stage feat patch (4 rows x 16 cols x 256 ch f32) into both f16 layouts
  const float* fb = feat + (size_t)bb * (CDIM * 16384) + (h * 4) * 128 + w4 * 16;
#pragma unroll
  for (int it = 0; it < 16; ++it) {
    int e = it * 256 + t, j4 = e & 3, r = (e >> 2) & 3, ci = e >> 4;
    float4 v = *(const float4*)(fb + (size_t)ci * 16384 + r * 128 + j4 * 4);
    f16x4 hv;
    hv[0] = (f16)v.x; hv[1] = (f16)v.y; hv[2] = (f16)v.z; hv[3] = (f16)v.w;
    *(f16x4*)(featb_cip + j4 * 4128 + ci * 16 + r * 4) = hv;  // p = r*4 + 0..3
    int pb = j4 * 4224 + ci;
    featb_pci[pb + (r * 4 + 0) * 264] = hv[0];
    featb_pci[pb + (r * 4 + 1) * 264] = hv[1];
    featb_pci[pb + (r * 4 + 2) * 264] = hv[2];
    featb_pci[pb + (r * 4 + 3) * 264] = hv[3];
  }
  __syncthreads();

  // ---- P3: logits via MFMA. A from global (L2-hot qk), rows 8-15 alias 0-7 ----
  const f16* qkg = qk + ((size_t)(bz * 1024 + pixb + w) * 8 + (l15 & 7)) * CDIM;
  const f16* fpci = featb_pci + w * 4224 + l15 * 264;
  f32x4 acc = {};
#pragma unroll
  for (int kb = 0; kb < 8; ++kb) {
    f16x8 a = *(const f16x8*)(qkg + kb * 32 + h4 * 8);          // A[hd][ci]
    f16x8 bf = *(const f16x8*)(fpci + kb * 32 + h4 * 8);        // B[ci][p]
    acc = MFMA(a, bf, acc);
  }
  // ---- softmax over p (= lane&15), hd = 4*h4 + reg (h4<2 real, rest dupes) ----
  float at[4];
#pragma unroll
  for (int r = 0; r < 4; ++r) {
    float m = acc[r];
    m = fmaxf(m, __shfl_xor(m, 1, 64));
    m = fmaxf(m, __shfl_xor(m, 2, 64));
    m = fmaxf(m, __shfl_xor(m, 4, 64));
    m = fmaxf(m, __shfl_xor(m, 8, 64));
    float e = __expf(acc[r] - m);
    float s = e;
    s += __shfl_xor(s, 1, 64);
    s += __shfl_xor(s, 2, 64);
    s += __shfl_xor(s, 4, 64);
    s += __shfl_xor(s, 8, 64);
    at[r] = e / s;
  }
  if (h4 < 2) {
#pragma unroll
    for (int r = 0; r < 4; ++r) attn_l[(w * 16 + h4 * 4 + r) * 32 + l15] = (f16)at[r];
  }
  // ---- P5: fa[ci][hd] = feat[ci][p pad32] @ attnT[p][hd] (same-wave RAW on attn_l) ----
  f16x8 bfr = *(const f16x8*)(attn_l + (w * 16 + l15) * 32 + h4 * 8);  // B[p][hd]
  const f16* fw = featb_cip + w * 4128;
  f32x4 zero = {};
#pragma unroll
  for (int mt = 0; mt < 16; ++mt) {
    f16x8 a5 = *(const f16x8*)(fw + (mt * 16 + l15) * 16 + h4 * 8);    // A[ci][p]
    f32x4 d = MFMA(a5, bfr, zero);
    if (l15 < 8) {  // n = l15 = hd (0..7 real)
      int ci0 = mt * 16 + h4 * 4;
      union { f16 h[4]; unsigned long long u; } P;
      P.h[0] = (f16)d[0]; P.h[1] = (f16)d[1]; P.h[2] = (f16)d[2]; P.h[3] = (f16)d[3];
      *(unsigned long long*)(fa + ((size_t)(bz * 8 + l15) * 1024 + pixb + w) * CDIM + ci0) =
          P.u;
    }
  }
}

// ---------------- K3: out[c][pix] = (wv @ fa + bv) * gw ----------------
// grid (16 pix-64, 8 hd, nb) x 256. M=64pix, N=32c, K=256ci.
__global__ __launch_bounds__(256) void k_out(const f16* __restrict__ fa,
                                             const f16* __restrict__ wvh,
                                             const float* __restrict__ bv,
                                             const float* __restrict__ gw,
                                             float* __restrict__ out, int b0) {
  __shared__ __align__(16) f16 wv_l[32 * 264];  // [c][256ci +8pad] 16896 B
  __shared__ __align__(16) f16 fa_l[64 * 40];   // [pix][32ci +8pad] 5120 B
  const int t = threadIdx.x;
  const int p16 = blockIdx.x, hd = blockIdx.y, bz = blockIdx.z;
  const int bb = b0 + bz;
  const int lane = t & 63, wid = t >> 6, l15 = lane & 15, h4 = lane >> 4;
#pragma unroll
  for (int it = 0; it < 4; ++it) {
    int e = it * 256 + t, c = e >> 5, ch = e & 31;
    *(f16x8*)(wv_l + c * 264 + ch * 8) =
        *(const f16x8*)(wvh + (size_t)(hd * 32 + c) * CDIM + ch * 8);
  }
  f32x4 acc[2] = {};
  for (int kb = 0; kb < 8; ++kb) {
    __syncthreads();
    {
      int pixl = t >> 2, q = t & 3;
      *(f16x8*)(fa_l + pixl * 40 + q * 8) =
          *(const f16x8*)(fa + ((size_t)(bz * 8 + hd) * 1024 + p16 * 64 + pixl) * CDIM +
                          kb * 32 + q * 8);
    }
    __syncthreads();
    f16x8 a = *(const f16x8*)(fa_l + (wid * 16 + l15) * 40 + h4 * 8);   // A[pix][ci]
#pragma unroll
    for (int nt = 0; nt < 2; ++nt) {
      f16x8 b = *(const f16x8*)(wv_l + (nt * 16 + l15) * 264 + kb * 32 + h4 * 8);  // B[ci][c]
      acc[nt] = MFMA(a, b, acc[nt]);
    }
  }
  int pix0 = p16 * 64 + wid * 16 + h4 * 4;
  float4 g = *(const float4*)(gw + bz * 1024 + pix0);
#pragma unroll
  for (int nt = 0; nt < 2; ++nt) {
    int c = hd * 32 + nt * 16 + l15;
    float bvc = bv[c];
    float4 o;
    o.x = (acc[nt][0] + bvc) * g.x;
    o.y = (acc[nt][1] + bvc) * g.y;
    o.z = (acc[nt][2] + bvc) * g.z;
    o.w = (acc[nt][3] + bvc) * g.w;
    *(float4*)(out + (size_t)(bb * CDIM + c) * 1024 + pix0) = o;
  }
}

// ---------------- launcher ----------------
extern "C" void kernel_launch(void* const* d_in, const int* in_sizes, int n_in,
                              void* d_out, int out_size, void* d_ws, size_t ws_size,
                              hipStream_t stream) {
  const float* x = (const float*)d_in[0];
  const float* feat = (const float*)d_in[1];
  const float* wq = (const float*)d_in[2];
  const float* bq = (const float*)d_in[3];
  const float* wk = (const float*)d_in[4];
  // d_in[5] = bk: constant over grid positions -> cancels in softmax, unused
  const float* wv = (const float*)d_in[6];
  const float* bv = (const float*)d_in[7];
  const float* wg = (const float*)d_in[8];
  const float* bg = (const float*)d_in[9];
  float* out = (float*)d_out;

  char* ws = (char*)d_ws;
  f16* W2h = (f16*)ws;                 // 1,048,576 B
  float* b2 = (float*)(ws + 1048576);  //     8,192 B
  f16* wvh = (f16*)(ws + 1056768);     //   131,072 B
  char* dyn = ws + 1187840;

  k_prep_w2<<<dim3(32, 8), 256, 0, stream>>>(wq, bq, wk, W2h, b2);
  k_cvt_wv<<<64, 256, 0, stream>>>(wv, wvh);

  const size_t QK = 4194304, FA = 4194304, GW = 4096;  // per batch
  if (ws_size >= 1187840 + 8 * (QK + FA + GW)) {
    f16* qk = (f16*)dyn;
    f16* fa = (f16*)(dyn + 8 * QK);
    float* gwp = (float*)(dyn + 8 * (QK + FA));
    k_qkw2<<<dim3(16, 8, 8), 256, 0, stream>>>(x, W2h, b2, wg, bg, qk, gwp, 0);
    k_attn<<<dim3(32, 8, 8), 256, 0, stream>>>(feat, qk, fa, 0);
    k_out<<<dim3(16, 8, 8), 256, 0, stream>>>(fa, wvh, bv, gwp, out, 0);
  } else {  // per-batch fallback (9.6 MB workspace)
    f16* qk = (f16*)dyn;
    f16* fa = (f16*)(dyn + QK);
    float* gwp = (float*)(dyn + QK + FA);
    for (int b = 0; b < 8; ++b) {
      k_qkw2<<<dim3(16, 8, 1), 256, 0, stream>>>(x, W2h, b2, wg, bg, qk, gwp, b);
      k_attn<<<dim3(32, 8, 1), 256, 0, stream>>>(feat, qk, fa, b);
      k_out<<<dim3(16, 8, 1), 256, 0, stream>>>(fa, wvh, bv, gwp, out, b);
    }
  }
}